// Round 5
// baseline (840.089 us; speedup 1.0000x reference)
//
#include <hip/hip_runtime.h>

// GCN forward: 2× (GCNConv) + mean-pool + linear head.
// Pipeline per call (ws is re-poisoned every call, so CSR is rebuilt each time):
//   count in-deg -> dinv -> exclusive scan -> scatter (CSR by dst)
//   t = bf16((x@W1)*dinv) ; h1 = relu((sum_in t + t[self])*dinv + b1)   [h1 f32]
//   t = bf16((h1@W2)*dinv); per-node scalar = ((sum_in t + t[self])*dinv + b2)·Wl
//   graph mean of scalars + bl -> out[512]
//
// R2: edge loop unrolled x8 -> 335->245 us per agg (latency-bound).
// R3: unroll x16 REGRESSED; reverted to x8.
// R4: bf16 t tables: FETCH halved, time flat -> bound by per-wave
//     outstanding-load slots x latency, not bytes.
// R5: 4 edges per gather instruction (4x16-lane groups, uint4/lane = one
//     256B bf16 row per quarter). 8 instrs in flight now cover 32 edges
//     (was 8). Quarter partials folded with shfl_xor(16/32).

__device__ __forceinline__ unsigned bf16pair(float a, float b) {
    unsigned ua = __float_as_uint(a);
    unsigned ub = __float_as_uint(b);
    unsigned ra = (ua + 0x7FFFu + ((ua >> 16) & 1u)) >> 16;
    unsigned rb = (ub + 0x7FFFu + ((ub >> 16) & 1u)) & 0xFFFF0000u;
    return ra | rb;
}

__global__ void k_count(const int* __restrict__ dst, int* __restrict__ cnt, int E) {
    int e = blockIdx.x * blockDim.x + threadIdx.x;
    if (e < E) atomicAdd(&cnt[dst[e]], 1);
}

__global__ void k_dinv(const int* __restrict__ cnt, float* __restrict__ dinv, int N) {
    int i = blockIdx.x * blockDim.x + threadIdx.x;
    if (i < N) dinv[i] = 1.0f / sqrtf((float)cnt[i] + 1.0f);  // +1 self loop
}

// Exclusive scan of cnt[N] -> rp[N]; per-chunk totals to bsum.
__global__ void k_scan_a(const int* __restrict__ cnt, int* __restrict__ rp,
                         int* __restrict__ bsum, int N) {
    __shared__ int tmp[1024];
    int i = blockIdx.x * 1024 + threadIdx.x;
    int v = (i < N) ? cnt[i] : 0;
    tmp[threadIdx.x] = v;
    __syncthreads();
    for (int off = 1; off < 1024; off <<= 1) {
        int t = (threadIdx.x >= off) ? tmp[threadIdx.x - off] : 0;
        __syncthreads();
        tmp[threadIdx.x] += t;
        __syncthreads();
    }
    if (i < N) rp[i] = (threadIdx.x == 0) ? 0 : tmp[threadIdx.x - 1];
    if (threadIdx.x == 1023) bsum[blockIdx.x] = tmp[1023];
}

// Exclusive scan of chunk totals (nb <= 128).
__global__ void k_scan_b(int* __restrict__ bsum, int nb) {
    __shared__ int tmp[128];
    int t = threadIdx.x;
    int v = (t < nb) ? bsum[t] : 0;
    tmp[t] = v;
    __syncthreads();
    for (int off = 1; off < 128; off <<= 1) {
        int u = (t >= off) ? tmp[t - off] : 0;
        __syncthreads();
        tmp[t] += u;
        __syncthreads();
    }
    if (t < nb) bsum[t] = (t == 0) ? 0 : tmp[t - 1];
}

__global__ void k_scan_c(int* __restrict__ rp, const int* __restrict__ bsum,
                         int* __restrict__ cur, int N, int E) {
    int i = blockIdx.x * blockDim.x + threadIdx.x;
    if (i < N) {
        int v = rp[i] + bsum[i >> 10];
        rp[i] = v;
        cur[i] = v;
    } else if (i == N) {
        rp[N] = E;
    }
}

__global__ void k_scatter(const int* __restrict__ src, const int* __restrict__ dst,
                          int* __restrict__ cur, int* __restrict__ srt, int E) {
    int e = blockIdx.x * blockDim.x + threadIdx.x;
    if (e < E) {
        int d = dst[e];
        int pos = atomicAdd(&cur[d], 1);
        srt[pos] = src[e];
    }
}

// Cb[r][:] = bf16( (A[r][:] @ B) * dinv[r] );  A: N x 128 f32, B: 128 x 128 f32.
// Cb rows are 64 uints (2 bf16 each). Classic 128x128 block, 8x8/thread, BK=8.
__global__ __launch_bounds__(256) void k_mm_scale(
    const float* __restrict__ A, const float* __restrict__ B,
    const float* __restrict__ dinv, unsigned* __restrict__ Cb, int N)
{
    __shared__ float As[8][128];   // [k][m] (transposed store)
    __shared__ float Bs[8][128];   // [k][n]
    int tid = threadIdx.x;
    int row0 = blockIdx.x * 128;
    int a_row = tid >> 1;            // 0..127
    int a_col = (tid & 1) * 4;       // 0 or 4
    int b_row = tid >> 5;            // 0..7
    int b_col = (tid & 31) * 4;      // 0..124
    int tx = tid & 15;               // col group (8 cols each)
    int ty = tid >> 4;               // row group (8 rows each)

    float acc[8][8];
#pragma unroll
    for (int i = 0; i < 8; ++i)
#pragma unroll
        for (int j = 0; j < 8; ++j) acc[i][j] = 0.0f;

    for (int k0 = 0; k0 < 128; k0 += 8) {
        int gr = row0 + a_row;
        if (gr > N - 1) gr = N - 1;   // clamp: OOB rows discarded at store
        float4 av = *(const float4*)(A + (size_t)gr * 128 + k0 + a_col);
        float4 bv = *(const float4*)(B + (size_t)(k0 + b_row) * 128 + b_col);
        As[a_col + 0][a_row] = av.x;
        As[a_col + 1][a_row] = av.y;
        As[a_col + 2][a_row] = av.z;
        As[a_col + 3][a_row] = av.w;
        *(float4*)&Bs[b_row][b_col] = bv;
        __syncthreads();
#pragma unroll
        for (int kk = 0; kk < 8; ++kk) {
            float a[8], b[8];
#pragma unroll
            for (int i = 0; i < 8; ++i) a[i] = As[kk][ty * 8 + i];
#pragma unroll
            for (int j = 0; j < 8; ++j) b[j] = Bs[kk][tx * 8 + j];
#pragma unroll
            for (int i = 0; i < 8; ++i)
#pragma unroll
                for (int j = 0; j < 8; ++j)
                    acc[i][j] = fmaf(a[i], b[j], acc[i][j]);
        }
        __syncthreads();
    }

#pragma unroll
    for (int i = 0; i < 8; ++i) {
        int r = row0 + ty * 8 + i;
        if (r < N) {
            float s = dinv[r];
            uint4 o;
            o.x = bf16pair(acc[i][0] * s, acc[i][1] * s);
            o.y = bf16pair(acc[i][2] * s, acc[i][3] * s);
            o.z = bf16pair(acc[i][4] * s, acc[i][5] * s);
            o.w = bf16pair(acc[i][6] * s, acc[i][7] * s);
            *(uint4*)(Cb + (size_t)r * 64 + tx * 4) = o;
        }
    }
}

// Quarter-split edge accumulation: lane = 16*quarter + sub. Each gather
// instruction loads 4 rows (one per quarter, uint4 = 16B/lane); 8 instrs in
// flight = 32 edges. Partial sums folded across quarters with shfl_xor;
// afterwards EVERY lane holds the full f32 sums of features [8*sub, 8*sub+8)
// (including the self-loop row).
__device__ __forceinline__ void edge_accum_q(
    const unsigned* __restrict__ t, const int* __restrict__ srt,
    int s0, int s1, int node, int quarter, int sub, float* __restrict__ acc)
{
    int col = sub * 4;   // uint offset within the 64-uint row
#pragma unroll
    for (int f = 0; f < 8; ++f) acc[f] = 0.0f;

    int e = s0;
    while (e + 32 <= s1) {
        int idx[8];
#pragma unroll
        for (int j = 0; j < 8; ++j) idx[j] = srt[e + j * 4 + quarter];
        uint4 w[8];
#pragma unroll
        for (int j = 0; j < 8; ++j)
            w[j] = *(const uint4*)(t + (size_t)idx[j] * 64 + col);
#pragma unroll
        for (int j = 0; j < 8; ++j) {
            acc[0] += __uint_as_float(w[j].x << 16);
            acc[1] += __uint_as_float(w[j].x & 0xFFFF0000u);
            acc[2] += __uint_as_float(w[j].y << 16);
            acc[3] += __uint_as_float(w[j].y & 0xFFFF0000u);
            acc[4] += __uint_as_float(w[j].z << 16);
            acc[5] += __uint_as_float(w[j].z & 0xFFFF0000u);
            acc[6] += __uint_as_float(w[j].w << 16);
            acc[7] += __uint_as_float(w[j].w & 0xFFFF0000u);
        }
        e += 32;
    }
    if (e < s1) {                      // masked batch covers rem in [1,31]
        int last = s1 - 1;
        int idx[8];
        float m[8];
#pragma unroll
        for (int j = 0; j < 8; ++j) {
            int k = e + j * 4 + quarter;
            m[j] = (k < s1) ? 1.0f : 0.0f;
            idx[j] = srt[k < last ? k : last];   // clamp: dup gathers are L1 hits
        }
        uint4 w[8];
#pragma unroll
        for (int j = 0; j < 8; ++j)
            w[j] = *(const uint4*)(t + (size_t)idx[j] * 64 + col);
#pragma unroll
        for (int j = 0; j < 8; ++j) {
            acc[0] = fmaf(m[j], __uint_as_float(w[j].x << 16), acc[0]);
            acc[1] = fmaf(m[j], __uint_as_float(w[j].x & 0xFFFF0000u), acc[1]);
            acc[2] = fmaf(m[j], __uint_as_float(w[j].y << 16), acc[2]);
            acc[3] = fmaf(m[j], __uint_as_float(w[j].y & 0xFFFF0000u), acc[3]);
            acc[4] = fmaf(m[j], __uint_as_float(w[j].z << 16), acc[4]);
            acc[5] = fmaf(m[j], __uint_as_float(w[j].z & 0xFFFF0000u), acc[5]);
            acc[6] = fmaf(m[j], __uint_as_float(w[j].w << 16), acc[6]);
            acc[7] = fmaf(m[j], __uint_as_float(w[j].w & 0xFFFF0000u), acc[7]);
        }
    }

    // Fold the 4 quarter-partials (all lanes end with the full sum).
#pragma unroll
    for (int f = 0; f < 8; ++f) {
        acc[f] += __shfl_xor(acc[f], 16);
        acc[f] += __shfl_xor(acc[f], 32);
    }
    // Self-loop row, added once (post-fold).
    uint4 ws = *(const uint4*)(t + (size_t)node * 64 + col);
    acc[0] += __uint_as_float(ws.x << 16);
    acc[1] += __uint_as_float(ws.x & 0xFFFF0000u);
    acc[2] += __uint_as_float(ws.y << 16);
    acc[3] += __uint_as_float(ws.y & 0xFFFF0000u);
    acc[4] += __uint_as_float(ws.z << 16);
    acc[5] += __uint_as_float(ws.z & 0xFFFF0000u);
    acc[6] += __uint_as_float(ws.w << 16);
    acc[7] += __uint_as_float(ws.w & 0xFFFF0000u);
}

// One wave per node; h1 out in f32 (lanes 0-15 store 32B each).
__global__ __launch_bounds__(256) void k_agg1(
    const unsigned* __restrict__ t, const float* __restrict__ dinv,
    const int* __restrict__ rp, const int* __restrict__ srt,
    const float* __restrict__ b1, float* __restrict__ hout, int N)
{
    int wave = threadIdx.x >> 6;
    int lane = threadIdx.x & 63;
    int node = blockIdx.x * 4 + wave;
    if (node >= N) return;
    int quarter = lane >> 4;
    int sub = lane & 15;
    int s0 = rp[node], s1 = rp[node + 1];
    float acc[8];
    edge_accum_q(t, srt, s0, s1, node, quarter, sub, acc);
    float di = dinv[node];
    float4 bb0 = *(const float4*)(b1 + sub * 8);
    float4 bb1 = *(const float4*)(b1 + sub * 8 + 4);
    float4 o0, o1;
    o0.x = fmaxf(fmaf(acc[0], di, bb0.x), 0.0f);
    o0.y = fmaxf(fmaf(acc[1], di, bb0.y), 0.0f);
    o0.z = fmaxf(fmaf(acc[2], di, bb0.z), 0.0f);
    o0.w = fmaxf(fmaf(acc[3], di, bb0.w), 0.0f);
    o1.x = fmaxf(fmaf(acc[4], di, bb1.x), 0.0f);
    o1.y = fmaxf(fmaf(acc[5], di, bb1.y), 0.0f);
    o1.z = fmaxf(fmaf(acc[6], di, bb1.z), 0.0f);
    o1.w = fmaxf(fmaf(acc[7], di, bb1.w), 0.0f);
    if (quarter == 0) {
        *(float4*)(hout + (size_t)node * 128 + sub * 8) = o0;
        *(float4*)(hout + (size_t)node * 128 + sub * 8 + 4) = o1;
    }
}

// Layer-2 aggregation fused with the linear head.
__global__ __launch_bounds__(256) void k_agg2(
    const unsigned* __restrict__ t, const float* __restrict__ dinv,
    const int* __restrict__ rp, const int* __restrict__ srt,
    const float* __restrict__ b2, const float* __restrict__ Wl,
    const int* __restrict__ batch, float* __restrict__ gsum,
    int* __restrict__ gcnt, int N)
{
    int wave = threadIdx.x >> 6;
    int lane = threadIdx.x & 63;
    int node = blockIdx.x * 4 + wave;
    if (node >= N) return;
    int quarter = lane >> 4;
    int sub = lane & 15;
    int s0 = rp[node], s1 = rp[node + 1];
    float acc[8];
    edge_accum_q(t, srt, s0, s1, node, quarter, sub, acc);
    float di = dinv[node];
    float4 bb0 = *(const float4*)(b2 + sub * 8);
    float4 bb1 = *(const float4*)(b2 + sub * 8 + 4);
    float4 wl0 = *(const float4*)(Wl + sub * 8);
    float4 wl1 = *(const float4*)(Wl + sub * 8 + 4);
    float p = 0.0f;
    p += fmaf(acc[0], di, bb0.x) * wl0.x;
    p += fmaf(acc[1], di, bb0.y) * wl0.y;
    p += fmaf(acc[2], di, bb0.z) * wl0.z;
    p += fmaf(acc[3], di, bb0.w) * wl0.w;
    p += fmaf(acc[4], di, bb1.x) * wl1.x;
    p += fmaf(acc[5], di, bb1.y) * wl1.y;
    p += fmaf(acc[6], di, bb1.z) * wl1.z;
    p += fmaf(acc[7], di, bb1.w) * wl1.w;
    // sum over sub = 0..15 (quarters hold identical replicas; lane 0 correct)
    p += __shfl_down(p, 8);
    p += __shfl_down(p, 4);
    p += __shfl_down(p, 2);
    p += __shfl_down(p, 1);
    if (lane == 0) {
        int g = batch[node];
        atomicAdd(&gsum[g], p);
        atomicAdd(&gcnt[g], 1);
    }
}

__global__ void k_final(const float* __restrict__ gsum, const int* __restrict__ gcnt,
                        const float* __restrict__ bl, float* __restrict__ out, int G) {
    int g = blockIdx.x * blockDim.x + threadIdx.x;
    if (g < G) out[g] = gsum[g] / fmaxf((float)gcnt[g], 1.0f) + bl[0];
}

extern "C" void kernel_launch(void* const* d_in, const int* in_sizes, int n_in,
                              void* d_out, int out_size, void* d_ws, size_t ws_size,
                              hipStream_t stream)
{
    const float* x  = (const float*)d_in[0];
    const int*   ei = (const int*)d_in[1];
    // d_in[2] = edge_attr: unused by the reference
    const int*   batch = (const int*)d_in[3];
    const float* W1 = (const float*)d_in[4];
    const float* b1 = (const float*)d_in[5];
    const float* W2 = (const float*)d_in[6];
    const float* b2 = (const float*)d_in[7];
    const float* Wl = (const float*)d_in[8];
    const float* bl = (const float*)d_in[9];

    int N = in_sizes[0] / 128;
    int E = in_sizes[1] / 2;
    const int* src = ei;
    const int* dst = ei + E;

    char* ws = (char*)d_ws;
    size_t off = 0;
    auto alloc = [&](size_t bytes) -> void* {
        void* p = ws + off;
        off = (off + bytes + 255) & ~(size_t)255;
        return p;
    };
    unsigned* t  = (unsigned*)alloc((size_t)N * 64 * 4);   // bf16 rows (256 B)
    float* h1    = (float*)alloc((size_t)N * 128 * 4);
    int*   srt   = (int*)alloc((size_t)E * 4);
    int*   cnt   = (int*)alloc((size_t)N * 4);
    float* dinv  = (float*)alloc((size_t)N * 4);
    int*   rp    = (int*)alloc((size_t)(N + 1) * 4);
    int*   cur   = (int*)alloc((size_t)N * 4);
    int*   bsum  = (int*)alloc(1024 * 4);
    float* gsum  = (float*)alloc(512 * 4);
    int*   gcnt  = (int*)alloc(512 * 4);
    (void)ws_size;

    hipMemsetAsync(cnt, 0, (size_t)N * 4, stream);
    hipMemsetAsync(gsum, 0, 512 * 4, stream);
    hipMemsetAsync(gcnt, 0, 512 * 4, stream);

    int eb = (E + 255) / 256;
    int nb = (N + 255) / 256;
    k_count<<<eb, 256, 0, stream>>>(dst, cnt, E);
    k_dinv<<<nb, 256, 0, stream>>>(cnt, dinv, N);
    int nchunk = (N + 1023) / 1024;   // 98 <= 128 (k_scan_b capacity)
    k_scan_a<<<nchunk, 1024, 0, stream>>>(cnt, rp, bsum, N);
    k_scan_b<<<1, 128, 0, stream>>>(bsum, nchunk);
    k_scan_c<<<(N + 256) / 256, 256, 0, stream>>>(rp, bsum, cur, N, E);
    k_scatter<<<eb, 256, 0, stream>>>(src, dst, cur, srt, E);

    int mmb = (N + 127) / 128;
    k_mm_scale<<<mmb, 256, 0, stream>>>(x, W1, dinv, t, N);
    k_agg1<<<(N + 3) / 4, 256, 0, stream>>>(t, dinv, rp, srt, b1, h1, N);
    k_mm_scale<<<mmb, 256, 0, stream>>>(h1, W2, dinv, t, N);
    k_agg2<<<(N + 3) / 4, 256, 0, stream>>>(t, dinv, rp, srt, b2, Wl, batch, gsum, gcnt, N);
    k_final<<<2, 256, 0, stream>>>(gsum, gcnt, bl, (float*)d_out, 512);
}

// Round 6
// 635.718 us; speedup vs baseline: 1.3215x; 1.3215x over previous
//
#include <hip/hip_runtime.h>

// GCN forward: 2× (GCNConv) + mean-pool + linear head, f32.
//   count in-deg -> dinv -> exclusive scan -> scatter (CSR by dst)
//   t = (x@W1)*dinv ; agg1: h1 = relu((sum_in t + t[self])*dinv + b1),
//                     fused epilogue: q[v] = dinv[v] * (h1[v] . w2l)   [scalar!]
//     where w2l = W2 @ Wl (128-vector, precomputed by k_w2l)
//   agg2 (linear head collapsed): p[v] = dinv[v]*(sum_in q + q[v]); graph-mean
//   out[g] = mean_g(p) + b2.Wl + bl
//
// R2: edge loop unrolled x8: 335->245 us/agg (best gather config).
// R3/R5: deeper unrolls REGRESSED (occupancy drop). R4: bf16 halved bytes,
//   time flat -> aggs bound by per-CU random-access service rate, not bytes.
// R6: layer-2 collapsed through the linear head: q[N] scalar table (400 KB,
//   L2-resident) replaces 256B-row gathers + second matmul + h1 writes.

__global__ void k_count(const int* __restrict__ dst, int* __restrict__ cnt, int E) {
    int e = blockIdx.x * blockDim.x + threadIdx.x;
    if (e < E) atomicAdd(&cnt[dst[e]], 1);
}

__global__ void k_dinv(const int* __restrict__ cnt, float* __restrict__ dinv, int N) {
    int i = blockIdx.x * blockDim.x + threadIdx.x;
    if (i < N) dinv[i] = 1.0f / sqrtf((float)cnt[i] + 1.0f);  // +1 self loop
}

// w2l[i] = sum_j W2[i][j] * Wl[j]
__global__ void k_w2l(const float* __restrict__ W2, const float* __restrict__ Wl,
                      float* __restrict__ w2l) {
    int i = threadIdx.x;   // 128 threads
    float s = 0.0f;
    for (int j = 0; j < 128; ++j) s = fmaf(W2[i * 128 + j], Wl[j], s);
    w2l[i] = s;
}

// Exclusive scan of cnt[N] -> rp[N]; per-chunk totals to bsum.
__global__ void k_scan_a(const int* __restrict__ cnt, int* __restrict__ rp,
                         int* __restrict__ bsum, int N) {
    __shared__ int tmp[1024];
    int i = blockIdx.x * 1024 + threadIdx.x;
    int v = (i < N) ? cnt[i] : 0;
    tmp[threadIdx.x] = v;
    __syncthreads();
    for (int off = 1; off < 1024; off <<= 1) {
        int t = (threadIdx.x >= off) ? tmp[threadIdx.x - off] : 0;
        __syncthreads();
        tmp[threadIdx.x] += t;
        __syncthreads();
    }
    if (i < N) rp[i] = (threadIdx.x == 0) ? 0 : tmp[threadIdx.x - 1];
    if (threadIdx.x == 1023) bsum[blockIdx.x] = tmp[1023];
}

// Exclusive scan of chunk totals (nb <= 128).
__global__ void k_scan_b(int* __restrict__ bsum, int nb) {
    __shared__ int tmp[128];
    int t = threadIdx.x;
    int v = (t < nb) ? bsum[t] : 0;
    tmp[t] = v;
    __syncthreads();
    for (int off = 1; off < 128; off <<= 1) {
        int u = (t >= off) ? tmp[t - off] : 0;
        __syncthreads();
        tmp[t] += u;
        __syncthreads();
    }
    if (t < nb) bsum[t] = (t == 0) ? 0 : tmp[t - 1];
}

__global__ void k_scan_c(int* __restrict__ rp, const int* __restrict__ bsum,
                         int* __restrict__ cur, int N, int E) {
    int i = blockIdx.x * blockDim.x + threadIdx.x;
    if (i < N) {
        int v = rp[i] + bsum[i >> 10];
        rp[i] = v;
        cur[i] = v;
    } else if (i == N) {
        rp[N] = E;
    }
}

__global__ void k_scatter(const int* __restrict__ src, const int* __restrict__ dst,
                          int* __restrict__ cur, int* __restrict__ srt, int E) {
    int e = blockIdx.x * blockDim.x + threadIdx.x;
    if (e < E) {
        int d = dst[e];
        int pos = atomicAdd(&cur[d], 1);
        srt[pos] = src[e];
    }
}

// C[r][:] = (A[r][:] @ B) * dinv[r];  A: N x 128, B: 128 x 128 row-major.
// Classic 128x128 block, 8x8 per thread, BK=8.
__global__ __launch_bounds__(256) void k_mm_scale(
    const float* __restrict__ A, const float* __restrict__ B,
    const float* __restrict__ dinv, float* __restrict__ C, int N)
{
    __shared__ float As[8][128];   // [k][m] (transposed store)
    __shared__ float Bs[8][128];   // [k][n]
    int tid = threadIdx.x;
    int row0 = blockIdx.x * 128;
    int a_row = tid >> 1;            // 0..127
    int a_col = (tid & 1) * 4;       // 0 or 4
    int b_row = tid >> 5;            // 0..7
    int b_col = (tid & 31) * 4;      // 0..124
    int tx = tid & 15;               // col group (8 cols each)
    int ty = tid >> 4;               // row group (8 rows each)

    float acc[8][8];
#pragma unroll
    for (int i = 0; i < 8; ++i)
#pragma unroll
        for (int j = 0; j < 8; ++j) acc[i][j] = 0.0f;

    for (int k0 = 0; k0 < 128; k0 += 8) {
        int gr = row0 + a_row;
        if (gr > N - 1) gr = N - 1;   // clamp: OOB rows discarded at store
        float4 av = *(const float4*)(A + (size_t)gr * 128 + k0 + a_col);
        float4 bv = *(const float4*)(B + (size_t)(k0 + b_row) * 128 + b_col);
        As[a_col + 0][a_row] = av.x;
        As[a_col + 1][a_row] = av.y;
        As[a_col + 2][a_row] = av.z;
        As[a_col + 3][a_row] = av.w;
        *(float4*)&Bs[b_row][b_col] = bv;
        __syncthreads();
#pragma unroll
        for (int kk = 0; kk < 8; ++kk) {
            float a[8], b[8];
#pragma unroll
            for (int i = 0; i < 8; ++i) a[i] = As[kk][ty * 8 + i];
#pragma unroll
            for (int j = 0; j < 8; ++j) b[j] = Bs[kk][tx * 8 + j];
#pragma unroll
            for (int i = 0; i < 8; ++i)
#pragma unroll
                for (int j = 0; j < 8; ++j)
                    acc[i][j] = fmaf(a[i], b[j], acc[i][j]);
        }
        __syncthreads();
    }

#pragma unroll
    for (int i = 0; i < 8; ++i) {
        int r = row0 + ty * 8 + i;
        if (r < N) {
            float s = dinv[r];
            float4 o0 = {acc[i][0] * s, acc[i][1] * s, acc[i][2] * s, acc[i][3] * s};
            float4 o1 = {acc[i][4] * s, acc[i][5] * s, acc[i][6] * s, acc[i][7] * s};
            *(float4*)(C + (size_t)r * 128 + tx * 8) = o0;
            *(float4*)(C + (size_t)r * 128 + tx * 8 + 4) = o1;
        }
    }
}

// Edge accumulation with 8 gathers in flight (R2 best config): sum over
// in-edges (pre-scaled rows) + self row, float2 per lane.
__device__ __forceinline__ float2 edge_accum(
    const float* __restrict__ t, const int* __restrict__ srt,
    int s0, int s1, int node, int lane)
{
    float2 a0 = {0,0}, a1 = {0,0}, a2 = {0,0}, a3 = {0,0};
    int e = s0;
    int fo = lane * 2;
    while (e + 8 <= s1) {
        int idx[8];
#pragma unroll
        for (int j = 0; j < 8; ++j) idx[j] = srt[e + j];
        float2 v[8];
#pragma unroll
        for (int j = 0; j < 8; ++j)
            v[j] = *(const float2*)(t + (size_t)idx[j] * 128 + fo);
        a0.x += v[0].x; a0.y += v[0].y;  a1.x += v[1].x; a1.y += v[1].y;
        a2.x += v[2].x; a2.y += v[2].y;  a3.x += v[3].x; a3.y += v[3].y;
        a0.x += v[4].x; a0.y += v[4].y;  a1.x += v[5].x; a1.y += v[5].y;
        a2.x += v[6].x; a2.y += v[6].y;  a3.x += v[7].x; a3.y += v[7].y;
        e += 8;
    }
    if (e + 4 <= s1) {
        int idx[4];
#pragma unroll
        for (int j = 0; j < 4; ++j) idx[j] = srt[e + j];
        float2 v[4];
#pragma unroll
        for (int j = 0; j < 4; ++j)
            v[j] = *(const float2*)(t + (size_t)idx[j] * 128 + fo);
        a0.x += v[0].x; a0.y += v[0].y;  a1.x += v[1].x; a1.y += v[1].y;
        a2.x += v[2].x; a2.y += v[2].y;  a3.x += v[3].x; a3.y += v[3].y;
        e += 4;
    }
    for (; e < s1; ++e) {
        int s = srt[e];
        float2 v = *(const float2*)(t + (size_t)s * 128 + fo);
        a0.x += v.x; a0.y += v.y;
    }
    float2 vs = *(const float2*)(t + (size_t)node * 128 + fo);  // self loop
    float2 acc;
    acc.x = (a0.x + a1.x) + (a2.x + a3.x) + vs.x;
    acc.y = (a0.y + a1.y) + (a2.y + a3.y) + vs.y;
    return acc;
}

// One wave per node: h1 = relu((sum_in t + t[self])*dinv + b1), then the
// collapsed layer-2 projection q[node] = dinv * (h1 . w2l). Only q is stored.
__global__ __launch_bounds__(256) void k_agg1(
    const float* __restrict__ t, const float* __restrict__ dinv,
    const int* __restrict__ rp, const int* __restrict__ srt,
    const float* __restrict__ b1, const float* __restrict__ w2l,
    float* __restrict__ q, int N)
{
    int wave = threadIdx.x >> 6;
    int lane = threadIdx.x & 63;
    int node = blockIdx.x * 4 + wave;
    if (node >= N) return;
    int s0 = rp[node], s1 = rp[node + 1];
    float2 acc = edge_accum(t, srt, s0, s1, node, lane);
    float di = dinv[node];
    float2 bb = *(const float2*)(b1 + lane * 2);
    float2 ww = *(const float2*)(w2l + lane * 2);
    float hx = fmaxf(fmaf(acc.x, di, bb.x), 0.0f);
    float hy = fmaxf(fmaf(acc.y, di, bb.y), 0.0f);
    float p = hx * ww.x + hy * ww.y;
#pragma unroll
    for (int off = 32; off > 0; off >>= 1) p += __shfl_down(p, off);
    if (lane == 0) q[node] = p * di;
}

// Collapsed layer-2 aggregation + pooling: one THREAD per node over the
// scalar q table (400 KB, L2-resident). p[v] = dinv[v]*(sum_in q + q[v]).
__global__ __launch_bounds__(256) void k_agg2(
    const float* __restrict__ q, const float* __restrict__ dinv,
    const int* __restrict__ rp, const int* __restrict__ srt,
    const int* __restrict__ batch, float* __restrict__ gsum,
    int* __restrict__ gcnt, int N)
{
    int i = blockIdx.x * blockDim.x + threadIdx.x;
    if (i >= N) return;
    int s0 = rp[i], s1 = rp[i + 1];
    float a0 = 0.0f, a1 = 0.0f, a2 = 0.0f, a3 = 0.0f;
    int e = s0;
    for (; e + 4 <= s1; e += 4) {
        a0 += q[srt[e]];
        a1 += q[srt[e + 1]];
        a2 += q[srt[e + 2]];
        a3 += q[srt[e + 3]];
    }
    for (; e < s1; ++e) a0 += q[srt[e]];
    float p = dinv[i] * ((a0 + a1) + (a2 + a3) + q[i]);
    atomicAdd(&gsum[batch[i]], p);
    atomicAdd(&gcnt[batch[i]], 1);
}

// out[g] = gsum/cnt + b2.Wl + bl   (b2.Wl constant across nodes/graphs)
__global__ void k_final(const float* __restrict__ gsum, const int* __restrict__ gcnt,
                        const float* __restrict__ b2, const float* __restrict__ Wl,
                        const float* __restrict__ bl, float* __restrict__ out, int G) {
    int g = blockIdx.x * blockDim.x + threadIdx.x;
    if (g < G) {
        float c = 0.0f;
        for (int j = 0; j < 128; ++j) c = fmaf(b2[j], Wl[j], c);
        out[g] = gsum[g] / fmaxf((float)gcnt[g], 1.0f) + c + bl[0];
    }
}

extern "C" void kernel_launch(void* const* d_in, const int* in_sizes, int n_in,
                              void* d_out, int out_size, void* d_ws, size_t ws_size,
                              hipStream_t stream)
{
    const float* x  = (const float*)d_in[0];
    const int*   ei = (const int*)d_in[1];
    // d_in[2] = edge_attr: unused by the reference
    const int*   batch = (const int*)d_in[3];
    const float* W1 = (const float*)d_in[4];
    const float* b1 = (const float*)d_in[5];
    const float* W2 = (const float*)d_in[6];
    const float* b2 = (const float*)d_in[7];
    const float* Wl = (const float*)d_in[8];
    const float* bl = (const float*)d_in[9];

    int N = in_sizes[0] / 128;
    int E = in_sizes[1] / 2;
    const int* src = ei;
    const int* dst = ei + E;

    char* ws = (char*)d_ws;
    size_t off = 0;
    auto alloc = [&](size_t bytes) -> void* {
        void* p = ws + off;
        off = (off + bytes + 255) & ~(size_t)255;
        return p;
    };
    float* t    = (float*)alloc((size_t)N * 128 * 4);   // (x@W1)*dinv, f32
    float* q    = (float*)alloc((size_t)N * 4);         // collapsed layer-2 scalars
    int*   srt  = (int*)alloc((size_t)E * 4);
    int*   cnt  = (int*)alloc((size_t)N * 4);
    float* dinv = (float*)alloc((size_t)N * 4);
    int*   rp   = (int*)alloc((size_t)(N + 1) * 4);
    int*   cur  = (int*)alloc((size_t)N * 4);
    int*   bsum = (int*)alloc(1024 * 4);
    float* gsum = (float*)alloc(512 * 4);
    int*   gcnt = (int*)alloc(512 * 4);
    float* w2l  = (float*)alloc(128 * 4);
    (void)ws_size;

    hipMemsetAsync(cnt, 0, (size_t)N * 4, stream);
    hipMemsetAsync(gsum, 0, 512 * 4, stream);
    hipMemsetAsync(gcnt, 0, 512 * 4, stream);

    int eb = (E + 255) / 256;
    int nb = (N + 255) / 256;
    k_count<<<eb, 256, 0, stream>>>(dst, cnt, E);
    k_dinv<<<nb, 256, 0, stream>>>(cnt, dinv, N);
    k_w2l<<<1, 128, 0, stream>>>(W2, Wl, w2l);
    int nchunk = (N + 1023) / 1024;   // 98 <= 128 (k_scan_b capacity)
    k_scan_a<<<nchunk, 1024, 0, stream>>>(cnt, rp, bsum, N);
    k_scan_b<<<1, 128, 0, stream>>>(bsum, nchunk);
    k_scan_c<<<(N + 256) / 256, 256, 0, stream>>>(rp, bsum, cur, N, E);
    k_scatter<<<eb, 256, 0, stream>>>(src, dst, cur, srt, E);

    int mmb = (N + 127) / 128;
    k_mm_scale<<<mmb, 256, 0, stream>>>(x, W1, dinv, t, N);
    k_agg1<<<(N + 3) / 4, 256, 0, stream>>>(t, dinv, rp, srt, b1, w2l, q, N);
    k_agg2<<<nb, 256, 0, stream>>>(q, dinv, rp, srt, batch, gsum, gcnt, N);
    k_final<<<2, 256, 0, stream>>>(gsum, gcnt, b2, Wl, bl, (float*)d_out, 512);
}